// Round 4
// baseline (547.073 us; speedup 1.0000x reference)
//
#include <hip/hip_runtime.h>

#define B_    64
#define NI    2048
#define DK    16
#define NO    32
#define DOUT  32
#define EPSQ  1e-7f

// ---------- helpers ----------
__device__ __forceinline__ unsigned pack2_bf16(float a, float b) {
    unsigned ua = __float_as_uint(a);
    unsigned ub = __float_as_uint(b);
    ua = (ua + 0x7fffu + ((ua >> 16) & 1u)) >> 16;   // RNE
    ub = (ub + 0x7fffu + ((ub >> 16) & 1u)) >> 16;
    return ua | (ub << 16);
}
__device__ __forceinline__ float bf_lo(unsigned w) { return __uint_as_float(w << 16); }
__device__ __forceinline__ float bf_hi(unsigned w) { return __uint_as_float(w & 0xffff0000u); }

// ============================================================
// FAST PATH
// u_hat layout (bf16/ushort): idx = (((b*NI + i)*4 + j)*NO + o)*8 + e, d = j*8+e
// -> per (b,i): 4*NO rows of 8 ushorts (one uint4 each) = 128 uint4's.
// ============================================================

// Produce u_hat once. Block = one i, 512 threads.
// thread: o = t&31, q = (t>>5)&7 (d-quad), bh = t>>8 (wave-uniform b-half).
// W in VGPRs; x rows loaded as wave-uniform scalars (no LDS, no barriers).
__global__ __launch_bounds__(512)
void compute_uhat(const float* __restrict__ x, const float* __restrict__ W,
                  ushort* __restrict__ U)
{
    const int i = blockIdx.x;
    const int t = threadIdx.x;
    const int o = t & 31;
    const int q = (t >> 5) & 7;       // d = 4q .. 4q+3
    const int bh = __builtin_amdgcn_readfirstlane(t >> 8);  // 0/1, SGPR

    // W[o,i,4q:4q+4,0:16] -> 64 contiguous floats
    float w[64];
    {
        const float4* wp = (const float4*)(W + (((size_t)o * NI + i) * DOUT + q * 4) * DK);
        #pragma unroll
        for (int m = 0; m < 16; ++m) {
            float4 v = wp[m];
            w[4*m+0] = v.x; w[4*m+1] = v.y; w[4*m+2] = v.z; w[4*m+3] = v.w;
        }
    }

    const int j = q >> 1, half = q & 1;
    ushort* Ub = U + (((size_t)i * 4 + j) * NO + o) * 8 + half * 4;
    const size_t bstride = (size_t)NI * 4 * NO * 8;   // ushorts per b
    const float* xb = x + ((size_t)(bh * 32) * NI + i) * DK;

    #pragma unroll 2
    for (int bb = 0; bb < 32; ++bb) {
        const int b = bh * 32 + bb;
        const float* xr = xb + (size_t)bb * NI * DK;  // wave-uniform address
        float xv[16];
        #pragma unroll
        for (int k = 0; k < 16; ++k) xv[k] = xr[k];   // scalar loads

        float acc[4];
        #pragma unroll
        for (int dl = 0; dl < 4; ++dl) {
            const float* wr = &w[dl * 16];
            float a0 = wr[0] * xv[0], a1 = wr[1] * xv[1];
            #pragma unroll
            for (int k = 2; k < 16; k += 2) {
                a0 = fmaf(wr[k],     xv[k],     a0);
                a1 = fmaf(wr[k + 1], xv[k + 1], a1);
            }
            acc[dl] = a0 + a1;
        }

        uint2 pk;
        pk.x = pack2_bf16(acc[0], acc[1]);
        pk.y = pack2_bf16(acc[2], acc[3]);
        *(uint2*)(Ub + (size_t)b * bstride) = pk;
    }
}

// One routing iteration as a streaming pass over u_hat, depth-1 prefetch.
// Block = (b, i-slab of 128). 256 threads = 8 half-waves; lane = o.
// UNI=true: Vsum==0 -> c = 1/32 exactly (softmax of zeros); skip logit/softmax.
constexpr int BPB = 16;               // blocks per b
constexpr int IPH = NI / BPB / 8;     // i's per half-wave = 16

template<bool UNI>
__global__ __launch_bounds__(256)
void routing_stream(const ushort* __restrict__ U, const float* __restrict__ Vsum,
                    float* __restrict__ s_out)
{
    __shared__ float sblk[NO * DOUT]; // 4 KB
    const int t  = threadIdx.x;
    const int b  = blockIdx.x >> 4;
    const int i0 = (blockIdx.x & (BPB - 1)) * (NI / BPB);
    const int o  = t & 31;
    const int hw = t >> 5;

    for (int n = t; n < NO * DOUT; n += 256) sblk[n] = 0.f;

    float vs[DOUT];
    if (!UNI) {
        const float4* vp = (const float4*)(Vsum + ((size_t)b * NO + o) * DOUT);
        #pragma unroll
        for (int m = 0; m < 8; ++m) {
            float4 v = vp[m];
            vs[4*m+0] = v.x; vs[4*m+1] = v.y; vs[4*m+2] = v.z; vs[4*m+3] = v.w;
        }
    }
    float sacc[DOUT];
    #pragma unroll
    for (int d = 0; d < DOUT; ++d) sacc[d] = 0.f;

    __syncthreads();   // sblk zero-init visible

    // per (b,i): 4*NO uint4's; row j at [j*NO + o]
    const uint4* up = (const uint4*)U + ((size_t)b * NI + i0 + hw) * (4 * NO) + o;
    const size_t step = (size_t)8 * 4 * NO;   // advance i by 8

    uint4 cur[4];
    #pragma unroll
    for (int jj = 0; jj < 4; ++jj) cur[jj] = up[jj * NO];
    up += step;

    for (int ii = 0; ii < IPH; ++ii) {
        uint4 nxt[4];
        if (ii + 1 < IPH) {              // uniform branch
            #pragma unroll
            for (int jj = 0; jj < 4; ++jj) nxt[jj] = up[jj * NO];
            up += step;
        }

        const unsigned cw[16] = { cur[0].x, cur[0].y, cur[0].z, cur[0].w,
                                  cur[1].x, cur[1].y, cur[1].z, cur[1].w,
                                  cur[2].x, cur[2].y, cur[2].z, cur[2].w,
                                  cur[3].x, cur[3].y, cur[3].z, cur[3].w };

        float c;
        if (!UNI) {
            float l0 = 0.f, l1 = 0.f, l2 = 0.f, l3 = 0.f;
            #pragma unroll
            for (int m = 0; m < 16; m += 4) {
                const int d0 = (m >> 2) * 8;
                l0 = fmaf(vs[d0+0], bf_lo(cw[m+0]), l0);
                l0 = fmaf(vs[d0+1], bf_hi(cw[m+0]), l0);
                l1 = fmaf(vs[d0+2], bf_lo(cw[m+1]), l1);
                l1 = fmaf(vs[d0+3], bf_hi(cw[m+1]), l1);
                l2 = fmaf(vs[d0+4], bf_lo(cw[m+2]), l2);
                l2 = fmaf(vs[d0+5], bf_hi(cw[m+2]), l2);
                l3 = fmaf(vs[d0+6], bf_lo(cw[m+3]), l3);
                l3 = fmaf(vs[d0+7], bf_hi(cw[m+3]), l3);
            }
            const float logit = (l0 + l1) + (l2 + l3);

            float mx = logit;
            #pragma unroll
            for (int msk = 16; msk >= 1; msk >>= 1) mx = fmaxf(mx, __shfl_xor(mx, msk));
            const float e = __expf(logit - mx);
            float ssum = e;
            #pragma unroll
            for (int msk = 16; msk >= 1; msk >>= 1) ssum += __shfl_xor(ssum, msk);
            c = e / ssum;
        } else {
            c = 0.03125f;   // 1/32
        }

        #pragma unroll
        for (int m = 0; m < 16; ++m) {
            const int d0 = (m >> 2) * 8 + (m & 3) * 2;
            sacc[d0]     = fmaf(c, bf_lo(cw[m]), sacc[d0]);
            sacc[d0 + 1] = fmaf(c, bf_hi(cw[m]), sacc[d0 + 1]);
        }

        #pragma unroll
        for (int jj = 0; jj < 4; ++jj) cur[jj] = nxt[jj];
    }

    // reduce the wave's two half-waves (same (b,o), disjoint i)
    #pragma unroll
    for (int d = 0; d < DOUT; ++d) sacc[d] += __shfl_xor(sacc[d], 32);

    if ((t & 32) == 0) {
        #pragma unroll
        for (int d = 0; d < DOUT; ++d) atomicAdd(&sblk[o * DOUT + d], sacc[d]);
    }
    __syncthreads();

    float* sp = s_out + (size_t)b * NO * DOUT;
    for (int n = t; n < NO * DOUT; n += 256) atomicAdd(&sp[n], sblk[n]);
}

// v = squash(s); Vsum += v; last iteration writes v to out.
__global__ __launch_bounds__(256)
void squash_update(const float* __restrict__ s, float* __restrict__ Vsum,
                   float* __restrict__ out, int last)
{
    const int tid  = threadIdx.x;
    const int pair = blockIdx.x * 8 + (tid >> 5);
    const int d    = tid & 31;
    const int idx  = pair * DOUT + d;

    const float val = s[idx];
    float sq = val * val;
    #pragma unroll
    for (int msk = 16; msk >= 1; msk >>= 1) sq += __shfl_xor(sq, msk);

    const float scale = sq / (1.f + sq) * rsqrtf(sq + EPSQ);
    const float v = val * scale;

    if (last) out[idx] = v;
    else      Vsum[idx] += v;
}

// ============================================================
// FALLBACK PATH (fused recompute; used if ws too small)
// ============================================================
constexpr int BTILE  = 16;
constexpr int ITILE  = 32;
constexpr int CHUNKS = NI / ITILE;
constexpr int GB     = B_ / BTILE;
constexpr int WROW   = DOUT * DK + 4;

__global__ __launch_bounds__(512)
void routing_pass(const float* __restrict__ x, const float* __restrict__ W,
                  const float* __restrict__ Vsum, float* __restrict__ s_out)
{
    __shared__ float W_s[NO * WROW];
    const int tid   = threadIdx.x;
    const int o     = tid & 31;
    const int bl    = tid >> 5;
    const int chunk = blockIdx.x & (CHUNKS - 1);
    const int gb    = blockIdx.x / CHUNKS;
    const int b     = gb * BTILE + bl;

    float vs[DOUT];
    {
        const float4* vp = (const float4*)(Vsum + (size_t)(b * NO + o) * DOUT);
        #pragma unroll
        for (int qq = 0; qq < 8; ++qq) {
            float4 t2 = vp[qq];
            vs[4*qq+0] = t2.x; vs[4*qq+1] = t2.y; vs[4*qq+2] = t2.z; vs[4*qq+3] = t2.w;
        }
    }
    float sacc[DOUT];
    #pragma unroll
    for (int d = 0; d < DOUT; ++d) sacc[d] = 0.f;

    const int o_ld = tid >> 4;
    const int lpos = tid & 15;

    for (int ii = 0; ii < ITILE; ++ii) {
        const int i = chunk * ITILE + ii;
        __syncthreads();
        const float4* wsrc = (const float4*)W + ((size_t)o_ld * NI + i) * (DOUT * DK / 4);
        #pragma unroll
        for (int jj = 0; jj < 8; ++jj) {
            const int f4pos = lpos + 16 * jj;
            float4 v = wsrc[f4pos];
            *(float4*)&W_s[o_ld * WROW + f4pos * 4] = v;
        }
        __syncthreads();

        const float4* xg = (const float4*)(x + ((size_t)b * NI + i) * DK);
        const float4 xr0 = xg[0], xr1 = xg[1], xr2 = xg[2], xr3 = xg[3];

        float u[DOUT];
        float logit = 0.f;
        const float* wrow = &W_s[o * WROW];
        #pragma unroll
        for (int d = 0; d < DOUT; ++d) {
            const float4 w0 = *(const float4*)(wrow + d * DK + 0);
            const float4 w1 = *(const float4*)(wrow + d * DK + 4);
            const float4 w2 = *(const float4*)(wrow + d * DK + 8);
            const float4 w3 = *(const float4*)(wrow + d * DK + 12);
            float acc;
            acc  = w0.x * xr0.x + w0.y * xr0.y + w0.z * xr0.z + w0.w * xr0.w;
            acc += w1.x * xr1.x + w1.y * xr1.y + w1.z * xr1.z + w1.w * xr1.w;
            acc += w2.x * xr2.x + w2.y * xr2.y + w2.z * xr2.z + w2.w * xr2.w;
            acc += w3.x * xr3.x + w3.y * xr3.y + w3.z * xr3.z + w3.w * xr3.w;
            u[d]  = acc;
            logit = fmaf(vs[d], acc, logit);
        }

        float m = logit;
        #pragma unroll
        for (int msk = 16; msk >= 1; msk >>= 1) m = fmaxf(m, __shfl_xor(m, msk));
        const float e = __expf(logit - m);
        float ssum = e;
        #pragma unroll
        for (int msk = 16; msk >= 1; msk >>= 1) ssum += __shfl_xor(ssum, msk);
        const float c = e / ssum;

        #pragma unroll
        for (int d = 0; d < DOUT; ++d) sacc[d] = fmaf(c, u[d], sacc[d]);
    }

    float* sp = s_out + (size_t)(b * NO + o) * DOUT;
    #pragma unroll
    for (int d = 0; d < DOUT; ++d) atomicAdd(&sp[d], sacc[d]);
}

// ============================================================
extern "C" void kernel_launch(void* const* d_in, const int* in_sizes, int n_in,
                              void* d_out, int out_size, void* d_ws, size_t ws_size,
                              hipStream_t stream)
{
    const float* x = (const float*)d_in[0];   // [B, NI, DK]
    const float* W = (const float*)d_in[1];   // [NO, NI, DOUT, DK]
    float* out = (float*)d_out;               // [B, NO, DOUT]

    float* Vsum = (float*)d_ws;                       // 65536 floats
    float* s    = Vsum + (size_t)B_ * NO * DOUT;      // 65536 floats
    ushort* U   = (ushort*)((char*)d_ws + 512 * 1024);

    const size_t need = 512 * 1024 + (size_t)B_ * NI * NO * DOUT * sizeof(ushort);

    hipMemsetAsync(Vsum, 0, (size_t)B_ * NO * DOUT * sizeof(float), stream);

    if (ws_size >= need) {
        compute_uhat<<<dim3(NI), dim3(512), 0, stream>>>(x, W, U);
        for (int r = 0; r < 3; ++r) {
            hipMemsetAsync(s, 0, (size_t)B_ * NO * DOUT * sizeof(float), stream);
            if (r == 0)
                routing_stream<true><<<dim3(B_ * BPB), dim3(256), 0, stream>>>(U, Vsum, s);
            else
                routing_stream<false><<<dim3(B_ * BPB), dim3(256), 0, stream>>>(U, Vsum, s);
            squash_update<<<dim3(B_ * NO / 8), dim3(256), 0, stream>>>(s, Vsum, out, r == 2);
        }
    } else {
        for (int r = 0; r < 3; ++r) {
            hipMemsetAsync(s, 0, (size_t)B_ * NO * DOUT * sizeof(float), stream);
            routing_pass<<<dim3(GB * CHUNKS), dim3(512), 0, stream>>>(x, W, Vsum, s);
            squash_update<<<dim3(B_ * NO / 8), dim3(256), 0, stream>>>(s, Vsum, out, r == 2);
        }
    }
}

// Round 5
// 500.101 us; speedup vs baseline: 1.0939x; 1.0939x over previous
//
#include <hip/hip_runtime.h>

#define B_    64
#define NI    2048
#define DK    16
#define NO    32
#define DOUT  32
#define EPSQ  1e-7f

// ---------- helpers ----------
__device__ __forceinline__ unsigned pack2_bf16(float a, float b) {
    unsigned ua = __float_as_uint(a);
    unsigned ub = __float_as_uint(b);
    ua = (ua + 0x7fffu + ((ua >> 16) & 1u)) >> 16;   // RNE
    ub = (ub + 0x7fffu + ((ub >> 16) & 1u)) >> 16;
    return ua | (ub << 16);
}
__device__ __forceinline__ float bf_lo(unsigned w) { return __uint_as_float(w << 16); }
__device__ __forceinline__ float bf_hi(unsigned w) { return __uint_as_float(w & 0xffff0000u); }

// ============================================================
// FAST PATH
// u_hat layout (bf16/ushort): idx = (((b*NI + i)*4 + j)*NO + o)*8 + e, d = j*8+e
// -> per (b,i): 4*NO rows of 8 ushorts (one uint4 each) = 128 uint4's.
// ============================================================

// Produce u_hat = einsum('oidk,bik->boid') once. Block = one i, 512 threads.
// thread: o = t&31, q = (t>>5)&7 (d-quad), bh = t>>8 (b-half). W in regs, x via LDS.
// (round-3 version, measured 190 us; scalar-s_load variant regressed -> reverted)
__global__ __launch_bounds__(512)
void compute_uhat(const float* __restrict__ x, const float* __restrict__ W,
                  ushort* __restrict__ U)
{
    __shared__ float xs[B_ * DK];     // 4 KB
    const int i = blockIdx.x;
    const int t = threadIdx.x;

    if (t < 256) {
        const int b = t >> 2, k4 = t & 3;
        float4 v = *(const float4*)(x + ((size_t)b * NI + i) * DK + k4 * 4);
        *(float4*)&xs[b * DK + k4 * 4] = v;
    }

    const int o  = t & 31;
    const int q  = (t >> 5) & 7;      // d = 4q .. 4q+3
    const int bh = t >> 8;            // 0/1

    // W[o,i,4q:4q+4,0:16] -> 64 contiguous floats
    float w[64];
    {
        const float4* wp = (const float4*)(W + (((size_t)o * NI + i) * DOUT + q * 4) * DK);
        #pragma unroll
        for (int m = 0; m < 16; ++m) {
            float4 v = wp[m];
            w[4*m+0] = v.x; w[4*m+1] = v.y; w[4*m+2] = v.z; w[4*m+3] = v.w;
        }
    }
    __syncthreads();

    const int j = q >> 1, half = q & 1;

    for (int bb = 0; bb < 32; ++bb) {
        const int b = bh * 32 + bb;
        const float4* xv = (const float4*)&xs[b * DK];
        const float4 x0 = xv[0], x1 = xv[1], x2 = xv[2], x3 = xv[3];

        float acc[4];
        #pragma unroll
        for (int dl = 0; dl < 4; ++dl) {
            const float* wr = &w[dl * 16];
            float a;
            a  = wr[0]  * x0.x + wr[1]  * x0.y + wr[2]  * x0.z + wr[3]  * x0.w;
            a += wr[4]  * x1.x + wr[5]  * x1.y + wr[6]  * x1.z + wr[7]  * x1.w;
            a += wr[8]  * x2.x + wr[9]  * x2.y + wr[10] * x2.z + wr[11] * x2.w;
            a += wr[12] * x3.x + wr[13] * x3.y + wr[14] * x3.z + wr[15] * x3.w;
            acc[dl] = a;
        }

        uint2 pk;
        pk.x = pack2_bf16(acc[0], acc[1]);
        pk.y = pack2_bf16(acc[2], acc[3]);
        const size_t off = ((((size_t)b * NI + i) * 4 + j) * NO + o) * 8 + half * 4;
        *(uint2*)(U + off) = pk;      // 8-byte aligned
    }
}

// ---------- per-i routing math on 4 uint4 rows (one (b,i) for this lane's o) ----------
template<bool UNI>
__device__ __forceinline__ void proc_i(const uint4* cr, const float* vs, float* sacc)
{
    unsigned cw[16];
    #pragma unroll
    for (int jj = 0; jj < 4; ++jj) {
        cw[4*jj+0] = cr[jj].x; cw[4*jj+1] = cr[jj].y;
        cw[4*jj+2] = cr[jj].z; cw[4*jj+3] = cr[jj].w;
    }

    if (UNI) {
        // c uniform; accumulate raw u, caller scales by 1/32 at the end
        #pragma unroll
        for (int m = 0; m < 16; ++m) {
            const int d0 = (m >> 2) * 8 + (m & 3) * 2;
            sacc[d0]     += bf_lo(cw[m]);
            sacc[d0 + 1] += bf_hi(cw[m]);
        }
    } else {
        float l0 = 0.f, l1 = 0.f, l2 = 0.f, l3 = 0.f;
        #pragma unroll
        for (int m = 0; m < 16; m += 4) {
            const int d0 = (m >> 2) * 8;
            l0 = fmaf(vs[d0+0], bf_lo(cw[m+0]), l0);
            l0 = fmaf(vs[d0+1], bf_hi(cw[m+0]), l0);
            l1 = fmaf(vs[d0+2], bf_lo(cw[m+1]), l1);
            l1 = fmaf(vs[d0+3], bf_hi(cw[m+1]), l1);
            l2 = fmaf(vs[d0+4], bf_lo(cw[m+2]), l2);
            l2 = fmaf(vs[d0+5], bf_hi(cw[m+2]), l2);
            l3 = fmaf(vs[d0+6], bf_lo(cw[m+3]), l3);
            l3 = fmaf(vs[d0+7], bf_hi(cw[m+3]), l3);
        }
        const float logit = (l0 + l1) + (l2 + l3);

        // softmax over o = 32 lanes of this half-wave (xor masks <32 stay in-half)
        float mx = logit;
        #pragma unroll
        for (int msk = 16; msk >= 1; msk >>= 1) mx = fmaxf(mx, __shfl_xor(mx, msk));
        const float e = __expf(logit - mx);
        float ssum = e;
        #pragma unroll
        for (int msk = 16; msk >= 1; msk >>= 1) ssum += __shfl_xor(ssum, msk);
        const float c = e / ssum;

        #pragma unroll
        for (int m = 0; m < 16; ++m) {
            const int d0 = (m >> 2) * 8 + (m & 3) * 2;
            sacc[d0]     = fmaf(c, bf_lo(cw[m]), sacc[d0]);
            sacc[d0 + 1] = fmaf(c, bf_hi(cw[m]), sacc[d0 + 1]);
        }
    }
}

// One routing iteration as a streaming pass over u_hat.
// Block = (b, i-slab of 128). 256 threads = 8 half-waves; lane = o.
// Each half-wave processes 2 consecutive i per iteration (8 loads in flight/wave),
// depth-1 group prefetch. UNI=true: Vsum==0 -> c = 1/32 exactly; skip softmax.
constexpr int BPB = 16;               // blocks per b
constexpr int NIB = NI / BPB / 16;    // 8 group-iterations (16 i per group)

template<bool UNI>
__global__ __launch_bounds__(256)
void routing_stream(const ushort* __restrict__ U, const float* __restrict__ Vsum,
                    float* __restrict__ s_out)
{
    __shared__ float sblk[NO * DOUT]; // 4 KB
    const int t  = threadIdx.x;
    const int b  = blockIdx.x >> 4;
    const int i0 = (blockIdx.x & (BPB - 1)) * (NI / BPB);
    const int o  = t & 31;
    const int hw = t >> 5;            // 0..7

    for (int n = t; n < NO * DOUT; n += 256) sblk[n] = 0.f;

    float vs[DOUT];
    if (!UNI) {
        const float4* vp = (const float4*)(Vsum + ((size_t)b * NO + o) * DOUT);
        #pragma unroll
        for (int m = 0; m < 8; ++m) {
            float4 v = vp[m];
            vs[4*m+0] = v.x; vs[4*m+1] = v.y; vs[4*m+2] = v.z; vs[4*m+3] = v.w;
        }
    }
    float sacc[DOUT];
    #pragma unroll
    for (int d = 0; d < DOUT; ++d) sacc[d] = 0.f;

    __syncthreads();   // sblk zero-init visible

    // per (b,i): 4*NO uint4's; row j at [j*NO]; i+1 is +4*NO
    const uint4* up = (const uint4*)U + ((size_t)b * NI + i0 + 2 * hw) * (4 * NO) + o;
    const size_t step = (size_t)16 * 4 * NO;   // advance i by 16

    uint4 cur[8];
    #pragma unroll
    for (int jj = 0; jj < 4; ++jj) {
        cur[jj]     = up[jj * NO];
        cur[4 + jj] = up[4 * NO + jj * NO];
    }
    up += step;

    for (int ii = 0; ii < NIB; ++ii) {
        uint4 nxt[8];
        if (ii + 1 < NIB) {           // uniform branch
            #pragma unroll
            for (int jj = 0; jj < 4; ++jj) {
                nxt[jj]     = up[jj * NO];
                nxt[4 + jj] = up[4 * NO + jj * NO];
            }
            up += step;
        }

        proc_i<UNI>(&cur[0], vs, sacc);
        proc_i<UNI>(&cur[4], vs, sacc);

        #pragma unroll
        for (int jj = 0; jj < 8; ++jj) cur[jj] = nxt[jj];
    }

    if (UNI) {
        #pragma unroll
        for (int d = 0; d < DOUT; ++d) sacc[d] *= 0.03125f;   // c = 1/32
    }

    // reduce the wave's two half-waves (same (b,o), disjoint i)
    #pragma unroll
    for (int d = 0; d < DOUT; ++d) sacc[d] += __shfl_xor(sacc[d], 32);

    if ((t & 32) == 0) {
        #pragma unroll
        for (int d = 0; d < DOUT; ++d) atomicAdd(&sblk[o * DOUT + d], sacc[d]);
    }
    __syncthreads();

    float* sp = s_out + (size_t)b * NO * DOUT;
    for (int n = t; n < NO * DOUT; n += 256) atomicAdd(&sp[n], sblk[n]);
}

// v = squash(s); Vsum += v; last iteration writes v to out.
__global__ __launch_bounds__(256)
void squash_update(const float* __restrict__ s, float* __restrict__ Vsum,
                   float* __restrict__ out, int last)
{
    const int tid  = threadIdx.x;
    const int pair = blockIdx.x * 8 + (tid >> 5);
    const int d    = tid & 31;
    const int idx  = pair * DOUT + d;

    const float val = s[idx];
    float sq = val * val;
    #pragma unroll
    for (int msk = 16; msk >= 1; msk >>= 1) sq += __shfl_xor(sq, msk);

    const float scale = sq / (1.f + sq) * rsqrtf(sq + EPSQ);
    const float v = val * scale;

    if (last) out[idx] = v;
    else      Vsum[idx] += v;
}

// ============================================================
// FALLBACK PATH (fused recompute; used if ws too small)
// ============================================================
constexpr int BTILE  = 16;
constexpr int ITILE  = 32;
constexpr int CHUNKS = NI / ITILE;
constexpr int GB     = B_ / BTILE;
constexpr int WROW   = DOUT * DK + 4;

__global__ __launch_bounds__(512)
void routing_pass(const float* __restrict__ x, const float* __restrict__ W,
                  const float* __restrict__ Vsum, float* __restrict__ s_out)
{
    __shared__ float W_s[NO * WROW];
    const int tid   = threadIdx.x;
    const int o     = tid & 31;
    const int bl    = tid >> 5;
    const int chunk = blockIdx.x & (CHUNKS - 1);
    const int gb    = blockIdx.x / CHUNKS;
    const int b     = gb * BTILE + bl;

    float vs[DOUT];
    {
        const float4* vp = (const float4*)(Vsum + (size_t)(b * NO + o) * DOUT);
        #pragma unroll
        for (int qq = 0; qq < 8; ++qq) {
            float4 t2 = vp[qq];
            vs[4*qq+0] = t2.x; vs[4*qq+1] = t2.y; vs[4*qq+2] = t2.z; vs[4*qq+3] = t2.w;
        }
    }
    float sacc[DOUT];
    #pragma unroll
    for (int d = 0; d < DOUT; ++d) sacc[d] = 0.f;

    const int o_ld = tid >> 4;
    const int lpos = tid & 15;

    for (int ii = 0; ii < ITILE; ++ii) {
        const int i = chunk * ITILE + ii;
        __syncthreads();
        const float4* wsrc = (const float4*)W + ((size_t)o_ld * NI + i) * (DOUT * DK / 4);
        #pragma unroll
        for (int jj = 0; jj < 8; ++jj) {
            const int f4pos = lpos + 16 * jj;
            float4 v = wsrc[f4pos];
            *(float4*)&W_s[o_ld * WROW + f4pos * 4] = v;
        }
        __syncthreads();

        const float4* xg = (const float4*)(x + ((size_t)b * NI + i) * DK);
        const float4 xr0 = xg[0], xr1 = xg[1], xr2 = xg[2], xr3 = xg[3];

        float u[DOUT];
        float logit = 0.f;
        const float* wrow = &W_s[o * WROW];
        #pragma unroll
        for (int d = 0; d < DOUT; ++d) {
            const float4 w0 = *(const float4*)(wrow + d * DK + 0);
            const float4 w1 = *(const float4*)(wrow + d * DK + 4);
            const float4 w2 = *(const float4*)(wrow + d * DK + 8);
            const float4 w3 = *(const float4*)(wrow + d * DK + 12);
            float acc;
            acc  = w0.x * xr0.x + w0.y * xr0.y + w0.z * xr0.z + w0.w * xr0.w;
            acc += w1.x * xr1.x + w1.y * xr1.y + w1.z * xr1.z + w1.w * xr1.w;
            acc += w2.x * xr2.x + w2.y * xr2.y + w2.z * xr2.z + w2.w * xr2.w;
            acc += w3.x * xr3.x + w3.y * xr3.y + w3.z * xr3.z + w3.w * xr3.w;
            u[d]  = acc;
            logit = fmaf(vs[d], acc, logit);
        }

        float m = logit;
        #pragma unroll
        for (int msk = 16; msk >= 1; msk >>= 1) m = fmaxf(m, __shfl_xor(m, msk));
        const float e = __expf(logit - m);
        float ssum = e;
        #pragma unroll
        for (int msk = 16; msk >= 1; msk >>= 1) ssum += __shfl_xor(ssum, msk);
        const float c = e / ssum;

        #pragma unroll
        for (int d = 0; d < DOUT; ++d) sacc[d] = fmaf(c, u[d], sacc[d]);
    }

    float* sp = s_out + (size_t)(b * NO + o) * DOUT;
    #pragma unroll
    for (int d = 0; d < DOUT; ++d) atomicAdd(&sp[d], sacc[d]);
}

// ============================================================
extern "C" void kernel_launch(void* const* d_in, const int* in_sizes, int n_in,
                              void* d_out, int out_size, void* d_ws, size_t ws_size,
                              hipStream_t stream)
{
    const float* x = (const float*)d_in[0];   // [B, NI, DK]
    const float* W = (const float*)d_in[1];   // [NO, NI, DOUT, DK]
    float* out = (float*)d_out;               // [B, NO, DOUT]

    float* Vsum = (float*)d_ws;                       // 65536 floats
    float* s    = Vsum + (size_t)B_ * NO * DOUT;      // 65536 floats
    ushort* U   = (ushort*)((char*)d_ws + 512 * 1024);

    const size_t need = 512 * 1024 + (size_t)B_ * NI * NO * DOUT * sizeof(ushort);

    hipMemsetAsync(Vsum, 0, (size_t)B_ * NO * DOUT * sizeof(float), stream);

    if (ws_size >= need) {
        compute_uhat<<<dim3(NI), dim3(512), 0, stream>>>(x, W, U);
        for (int r = 0; r < 3; ++r) {
            hipMemsetAsync(s, 0, (size_t)B_ * NO * DOUT * sizeof(float), stream);
            if (r == 0)
                routing_stream<true><<<dim3(B_ * BPB), dim3(256), 0, stream>>>(U, Vsum, s);
            else
                routing_stream<false><<<dim3(B_ * BPB), dim3(256), 0, stream>>>(U, Vsum, s);
            squash_update<<<dim3(B_ * NO / 8), dim3(256), 0, stream>>>(s, Vsum, out, r == 2);
        }
    } else {
        for (int r = 0; r < 3; ++r) {
            hipMemsetAsync(s, 0, (size_t)B_ * NO * DOUT * sizeof(float), stream);
            routing_pass<<<dim3(GB * CHUNKS), dim3(512), 0, stream>>>(x, W, Vsum, s);
            squash_update<<<dim3(B_ * NO / 8), dim3(256), 0, stream>>>(s, Vsum, out, r == 2);
        }
    }
}

// Round 6
// 456.372 us; speedup vs baseline: 1.1987x; 1.0958x over previous
//
#include <hip/hip_runtime.h>

#define B_    64
#define NI    2048
#define DK    16
#define NO    32
#define DOUT  32
#define EPSQ  1e-7f

// ---------- helpers ----------
__device__ __forceinline__ unsigned pack2_bf16(float a, float b) {
    unsigned ua = __float_as_uint(a);
    unsigned ub = __float_as_uint(b);
    ua = (ua + 0x7fffu + ((ua >> 16) & 1u)) >> 16;   // RNE
    ub = (ub + 0x7fffu + ((ub >> 16) & 1u)) >> 16;
    return ua | (ub << 16);
}
__device__ __forceinline__ float bf_lo(unsigned w) { return __uint_as_float(w << 16); }
__device__ __forceinline__ float bf_hi(unsigned w) { return __uint_as_float(w & 0xffff0000u); }

// ============================================================
// FAST PATH
// u_hat layout (bf16/ushort): idx = (((b*NI + i)*4 + j)*NO + o)*8 + e, d = j*8+e
// -> per (b,i): 4*NO rows of 8 ushorts (one uint4 each) = 128 uint4's.
// ============================================================

constexpr int WSTRIDE = 516;   // 512 + 4 pad: one-time LDS read conflicts only

// Produce u_hat = einsum('oidk,bik->boid') once. Block = one i, 512 threads.
// thread: o = t&31, q = (t>>5)&7 (d-quad), bh = t>>8 (b-half).
// W staged GLOBAL->LDS with coalesced loads (16 lines/instr vs 64 for the
// direct scattered per-thread read), then LDS->regs once; x via LDS broadcast.
__global__ __launch_bounds__(512)
void compute_uhat(const float* __restrict__ x, const float* __restrict__ W,
                  ushort* __restrict__ U)
{
    __shared__ float Ws[NO * WSTRIDE];   // 66048 B
    __shared__ float xs[B_ * DK];        // 4096 B
    const int i = blockIdx.x;
    const int t = threadIdx.x;

    // stage x[0:64, i, 0:16] (4 KB)
    if (t < 256) {
        const int b = t >> 2, k4 = t & 3;
        float4 v = *(const float4*)(x + ((size_t)b * NI + i) * DK + k4 * 4);
        *(float4*)&xs[b * DK + k4 * 4] = v;
    }

    // stage W[:, i, :, :] (64 KB) coalesced: float4 p = (o<<7)|c, consecutive
    // lanes -> consecutive addresses within an o-chunk (2KB runs).
    #pragma unroll
    for (int jj = 0; jj < 8; ++jj) {
        const int p  = t + 512 * jj;     // 0..4095
        const int oo = p >> 7;           // o
        const int cc = p & 127;          // float4 within o-row (128 per row)
        float4 v = ((const float4*)(W + ((size_t)oo * NI + i) * (DOUT * DK)))[cc];
        *(float4*)&Ws[oo * WSTRIDE + cc * 4] = v;
    }

    const int o  = t & 31;
    const int q  = (t >> 5) & 7;      // d = 4q .. 4q+3
    const int bh = t >> 8;            // 0/1

    __syncthreads();

    // one-time LDS -> regs: W[o,i,4q:4q+4,0:16] = 64 consecutive floats
    float w[64];
    {
        const float* wr = &Ws[o * WSTRIDE + q * 64];
        #pragma unroll
        for (int m = 0; m < 16; ++m) {
            float4 v = *(const float4*)(wr + 4 * m);
            w[4*m+0] = v.x; w[4*m+1] = v.y; w[4*m+2] = v.z; w[4*m+3] = v.w;
        }
    }

    const int j = q >> 1, half = q & 1;

    for (int bb = 0; bb < 32; ++bb) {
        const int b = bh * 32 + bb;
        const float4* xv = (const float4*)&xs[b * DK];
        const float4 x0 = xv[0], x1 = xv[1], x2 = xv[2], x3 = xv[3];

        float acc[4];
        #pragma unroll
        for (int dl = 0; dl < 4; ++dl) {
            const float* wr = &w[dl * 16];
            float a;
            a  = wr[0]  * x0.x + wr[1]  * x0.y + wr[2]  * x0.z + wr[3]  * x0.w;
            a += wr[4]  * x1.x + wr[5]  * x1.y + wr[6]  * x1.z + wr[7]  * x1.w;
            a += wr[8]  * x2.x + wr[9]  * x2.y + wr[10] * x2.z + wr[11] * x2.w;
            a += wr[12] * x3.x + wr[13] * x3.y + wr[14] * x3.z + wr[15] * x3.w;
            acc[dl] = a;
        }

        uint2 pk;
        pk.x = pack2_bf16(acc[0], acc[1]);
        pk.y = pack2_bf16(acc[2], acc[3]);
        const size_t off = ((((size_t)b * NI + i) * 4 + j) * NO + o) * 8 + half * 4;
        *(uint2*)(U + off) = pk;      // 8-byte aligned
    }
}

// ---------- per-i routing math on 4 uint4 rows (one (b,i) for this lane's o) ----------
template<bool UNI>
__device__ __forceinline__ void proc_i(const uint4* cr, const float* vs, float* sacc)
{
    unsigned cw[16];
    #pragma unroll
    for (int jj = 0; jj < 4; ++jj) {
        cw[4*jj+0] = cr[jj].x; cw[4*jj+1] = cr[jj].y;
        cw[4*jj+2] = cr[jj].z; cw[4*jj+3] = cr[jj].w;
    }

    if (UNI) {
        // c uniform; accumulate raw u, caller scales by 1/32 at the end
        #pragma unroll
        for (int m = 0; m < 16; ++m) {
            const int d0 = (m >> 2) * 8 + (m & 3) * 2;
            sacc[d0]     += bf_lo(cw[m]);
            sacc[d0 + 1] += bf_hi(cw[m]);
        }
    } else {
        float l0 = 0.f, l1 = 0.f, l2 = 0.f, l3 = 0.f;
        #pragma unroll
        for (int m = 0; m < 16; m += 4) {
            const int d0 = (m >> 2) * 8;
            l0 = fmaf(vs[d0+0], bf_lo(cw[m+0]), l0);
            l0 = fmaf(vs[d0+1], bf_hi(cw[m+0]), l0);
            l1 = fmaf(vs[d0+2], bf_lo(cw[m+1]), l1);
            l1 = fmaf(vs[d0+3], bf_hi(cw[m+1]), l1);
            l2 = fmaf(vs[d0+4], bf_lo(cw[m+2]), l2);
            l2 = fmaf(vs[d0+5], bf_hi(cw[m+2]), l2);
            l3 = fmaf(vs[d0+6], bf_lo(cw[m+3]), l3);
            l3 = fmaf(vs[d0+7], bf_hi(cw[m+3]), l3);
        }
        const float logit = (l0 + l1) + (l2 + l3);

        // softmax over o = 32 lanes of this half-wave (xor masks <32 stay in-half)
        float mx = logit;
        #pragma unroll
        for (int msk = 16; msk >= 1; msk >>= 1) mx = fmaxf(mx, __shfl_xor(mx, msk));
        const float e = __expf(logit - mx);
        float ssum = e;
        #pragma unroll
        for (int msk = 16; msk >= 1; msk >>= 1) ssum += __shfl_xor(ssum, msk);
        const float c = e / ssum;

        #pragma unroll
        for (int m = 0; m < 16; ++m) {
            const int d0 = (m >> 2) * 8 + (m & 3) * 2;
            sacc[d0]     = fmaf(c, bf_lo(cw[m]), sacc[d0]);
            sacc[d0 + 1] = fmaf(c, bf_hi(cw[m]), sacc[d0 + 1]);
        }
    }
}

// One routing iteration as a streaming pass over u_hat.
// Block = (b, i-slab of 128). 256 threads = 8 half-waves; lane = o.
// Each half-wave processes 2 consecutive i per iteration, depth-1 group prefetch.
// UNI=true: Vsum==0 -> c = 1/32 exactly; skip softmax, scale once at end.
constexpr int BPB = 16;               // blocks per b
constexpr int NIB = NI / BPB / 16;    // 8 group-iterations (16 i per group)

template<bool UNI>
__global__ __launch_bounds__(256)
void routing_stream(const ushort* __restrict__ U, const float* __restrict__ Vsum,
                    float* __restrict__ s_out)
{
    __shared__ float sblk[NO * DOUT]; // 4 KB
    const int t  = threadIdx.x;
    const int b  = blockIdx.x >> 4;
    const int i0 = (blockIdx.x & (BPB - 1)) * (NI / BPB);
    const int o  = t & 31;
    const int hw = t >> 5;            // 0..7

    for (int n = t; n < NO * DOUT; n += 256) sblk[n] = 0.f;

    float vs[DOUT];
    if (!UNI) {
        const float4* vp = (const float4*)(Vsum + ((size_t)b * NO + o) * DOUT);
        #pragma unroll
        for (int m = 0; m < 8; ++m) {
            float4 v = vp[m];
            vs[4*m+0] = v.x; vs[4*m+1] = v.y; vs[4*m+2] = v.z; vs[4*m+3] = v.w;
        }
    }
    float sacc[DOUT];
    #pragma unroll
    for (int d = 0; d < DOUT; ++d) sacc[d] = 0.f;

    __syncthreads();   // sblk zero-init visible

    // per (b,i): 4*NO uint4's; row j at [j*NO]; i+1 is +4*NO
    const uint4* up = (const uint4*)U + ((size_t)b * NI + i0 + 2 * hw) * (4 * NO) + o;
    const size_t step = (size_t)16 * 4 * NO;   // advance i by 16

    uint4 cur[8];
    #pragma unroll
    for (int jj = 0; jj < 4; ++jj) {
        cur[jj]     = up[jj * NO];
        cur[4 + jj] = up[4 * NO + jj * NO];
    }
    up += step;

    for (int ii = 0; ii < NIB; ++ii) {
        uint4 nxt[8];
        if (ii + 1 < NIB) {           // uniform branch
            #pragma unroll
            for (int jj = 0; jj < 4; ++jj) {
                nxt[jj]     = up[jj * NO];
                nxt[4 + jj] = up[4 * NO + jj * NO];
            }
            up += step;
        }

        proc_i<UNI>(&cur[0], vs, sacc);
        proc_i<UNI>(&cur[4], vs, sacc);

        #pragma unroll
        for (int jj = 0; jj < 8; ++jj) cur[jj] = nxt[jj];
    }

    if (UNI) {
        #pragma unroll
        for (int d = 0; d < DOUT; ++d) sacc[d] *= 0.03125f;   // c = 1/32
    }

    // reduce the wave's two half-waves (same (b,o), disjoint i)
    #pragma unroll
    for (int d = 0; d < DOUT; ++d) sacc[d] += __shfl_xor(sacc[d], 32);

    if ((t & 32) == 0) {
        #pragma unroll
        for (int d = 0; d < DOUT; ++d) atomicAdd(&sblk[o * DOUT + d], sacc[d]);
    }
    __syncthreads();

    float* sp = s_out + (size_t)b * NO * DOUT;
    for (int n = t; n < NO * DOUT; n += 256) atomicAdd(&sp[n], sblk[n]);
}

// v = squash(s); Vsum += v; last iteration writes v to out.
__global__ __launch_bounds__(256)
void squash_update(const float* __restrict__ s, float* __restrict__ Vsum,
                   float* __restrict__ out, int last)
{
    const int tid  = threadIdx.x;
    const int pair = blockIdx.x * 8 + (tid >> 5);
    const int d    = tid & 31;
    const int idx  = pair * DOUT + d;

    const float val = s[idx];
    float sq = val * val;
    #pragma unroll
    for (int msk = 16; msk >= 1; msk >>= 1) sq += __shfl_xor(sq, msk);

    const float scale = sq / (1.f + sq) * rsqrtf(sq + EPSQ);
    const float v = val * scale;

    if (last) out[idx] = v;
    else      Vsum[idx] += v;
}

// ============================================================
// FALLBACK PATH (fused recompute; used if ws too small)
// ============================================================
constexpr int BTILE  = 16;
constexpr int ITILE  = 32;
constexpr int CHUNKS = NI / ITILE;
constexpr int GB     = B_ / BTILE;
constexpr int WROW   = DOUT * DK + 4;

__global__ __launch_bounds__(512)
void routing_pass(const float* __restrict__ x, const float* __restrict__ W,
                  const float* __restrict__ Vsum, float* __restrict__ s_out)
{
    __shared__ float W_s[NO * WROW];
    const int tid   = threadIdx.x;
    const int o     = tid & 31;
    const int bl    = tid >> 5;
    const int chunk = blockIdx.x & (CHUNKS - 1);
    const int gb    = blockIdx.x / CHUNKS;
    const int b     = gb * BTILE + bl;

    float vs[DOUT];
    {
        const float4* vp = (const float4*)(Vsum + (size_t)(b * NO + o) * DOUT);
        #pragma unroll
        for (int qq = 0; qq < 8; ++qq) {
            float4 t2 = vp[qq];
            vs[4*qq+0] = t2.x; vs[4*qq+1] = t2.y; vs[4*qq+2] = t2.z; vs[4*qq+3] = t2.w;
        }
    }
    float sacc[DOUT];
    #pragma unroll
    for (int d = 0; d < DOUT; ++d) sacc[d] = 0.f;

    const int o_ld = tid >> 4;
    const int lpos = tid & 15;

    for (int ii = 0; ii < ITILE; ++ii) {
        const int i = chunk * ITILE + ii;
        __syncthreads();
        const float4* wsrc = (const float4*)W + ((size_t)o_ld * NI + i) * (DOUT * DK / 4);
        #pragma unroll
        for (int jj = 0; jj < 8; ++jj) {
            const int f4pos = lpos + 16 * jj;
            float4 v = wsrc[f4pos];
            *(float4*)&W_s[o_ld * WROW + f4pos * 4] = v;
        }
        __syncthreads();

        const float4* xg = (const float4*)(x + ((size_t)b * NI + i) * DK);
        const float4 xr0 = xg[0], xr1 = xg[1], xr2 = xg[2], xr3 = xg[3];

        float u[DOUT];
        float logit = 0.f;
        const float* wrow = &W_s[o * WROW];
        #pragma unroll
        for (int d = 0; d < DOUT; ++d) {
            const float4 w0 = *(const float4*)(wrow + d * DK + 0);
            const float4 w1 = *(const float4*)(wrow + d * DK + 4);
            const float4 w2 = *(const float4*)(wrow + d * DK + 8);
            const float4 w3 = *(const float4*)(wrow + d * DK + 12);
            float acc;
            acc  = w0.x * xr0.x + w0.y * xr0.y + w0.z * xr0.z + w0.w * xr0.w;
            acc += w1.x * xr1.x + w1.y * xr1.y + w1.z * xr1.z + w1.w * xr1.w;
            acc += w2.x * xr2.x + w2.y * xr2.y + w2.z * xr2.z + w2.w * xr2.w;
            acc += w3.x * xr3.x + w3.y * xr3.y + w3.z * xr3.z + w3.w * xr3.w;
            u[d]  = acc;
            logit = fmaf(vs[d], acc, logit);
        }

        float m = logit;
        #pragma unroll
        for (int msk = 16; msk >= 1; msk >>= 1) m = fmaxf(m, __shfl_xor(m, msk));
        const float e = __expf(logit - m);
        float ssum = e;
        #pragma unroll
        for (int msk = 16; msk >= 1; msk >>= 1) ssum += __shfl_xor(ssum, msk);
        const float c = e / ssum;

        #pragma unroll
        for (int d = 0; d < DOUT; ++d) sacc[d] = fmaf(c, u[d], sacc[d]);
    }

    float* sp = s_out + (size_t)(b * NO + o) * DOUT;
    #pragma unroll
    for (int d = 0; d < DOUT; ++d) atomicAdd(&sp[d], sacc[d]);
}

// ============================================================
extern "C" void kernel_launch(void* const* d_in, const int* in_sizes, int n_in,
                              void* d_out, int out_size, void* d_ws, size_t ws_size,
                              hipStream_t stream)
{
    const float* x = (const float*)d_in[0];   // [B, NI, DK]
    const float* W = (const float*)d_in[1];   // [NO, NI, DOUT, DK]
    float* out = (float*)d_out;               // [B, NO, DOUT]

    float* Vsum = (float*)d_ws;                       // 65536 floats
    float* s    = Vsum + (size_t)B_ * NO * DOUT;      // 65536 floats
    ushort* U   = (ushort*)((char*)d_ws + 512 * 1024);

    const size_t need = 512 * 1024 + (size_t)B_ * NI * NO * DOUT * sizeof(ushort);

    hipMemsetAsync(Vsum, 0, (size_t)B_ * NO * DOUT * sizeof(float), stream);

    if (ws_size >= need) {
        compute_uhat<<<dim3(NI), dim3(512), 0, stream>>>(x, W, U);
        for (int r = 0; r < 3; ++r) {
            hipMemsetAsync(s, 0, (size_t)B_ * NO * DOUT * sizeof(float), stream);
            if (r == 0)
                routing_stream<true><<<dim3(B_ * BPB), dim3(256), 0, stream>>>(U, Vsum, s);
            else
                routing_stream<false><<<dim3(B_ * BPB), dim3(256), 0, stream>>>(U, Vsum, s);
            squash_update<<<dim3(B_ * NO / 8), dim3(256), 0, stream>>>(s, Vsum, out, r == 2);
        }
    } else {
        for (int r = 0; r < 3; ++r) {
            hipMemsetAsync(s, 0, (size_t)B_ * NO * DOUT * sizeof(float), stream);
            routing_pass<<<dim3(GB * CHUNKS), dim3(512), 0, stream>>>(x, W, Vsum, s);
            squash_update<<<dim3(B_ * NO / 8), dim3(256), 0, stream>>>(s, Vsum, out, r == 2);
        }
    }
}